// Round 1
// 1252.511 us; speedup vs baseline: 1.3501x; 1.3501x over previous
//
#include <hip/hip_runtime.h>
#include <cmath>

typedef unsigned short u16;
typedef unsigned short u16x2 __attribute__((ext_vector_type(2)));
typedef unsigned short u16x8 __attribute__((ext_vector_type(8)));
typedef short s16x8 __attribute__((ext_vector_type(8)));
typedef float f32x4 __attribute__((ext_vector_type(4)));
typedef float f32x2 __attribute__((ext_vector_type(2)));

#define B_SZ 16
#define HW 56
#define L_TOK 3136      // 56*56
#define C_DIM 512
#define NHEAD 16
#define DHEAD 32
#define WS7 7
#define NWIN 49
#define ROWS_TOTAL 50176   // 16*3136
#define MLP_DIM 2048

__device__ __forceinline__ float bf2f(u16 u) {
    union { unsigned int i; float f; } z;
    z.i = ((unsigned int)u) << 16;
    return z.f;
}
__device__ __forceinline__ u16 f2bf(float f) {
    union { float f; unsigned int i; } z;
    z.f = f;
    unsigned int r = z.i + 0x7fffu + ((z.i >> 16) & 1u);
    return (u16)(r >> 16);
}

// async global->LDS, 16B per lane; LDS dest = wave-uniform base + lane*16
__device__ __forceinline__ void gl_lds16(const u16* g, u16* l) {
    __builtin_amdgcn_global_load_lds(
        (const __attribute__((address_space(1))) unsigned int*)g,
        (__attribute__((address_space(3))) unsigned int*)l,
        16, 0, 0);
}

// ---------------------------------------------------------------------------
// 1) mod = silu(emb) @ adaLN_w + adaLN_b -> fp32 [16,3072]
// ---------------------------------------------------------------------------
__global__ __launch_bounds__(256)
void mod_kernel(const float* __restrict__ emb, const float* __restrict__ w,
                const float* __restrict__ bias, float* __restrict__ mod)
{
    int b = blockIdx.y;
    int o = blockIdx.x * 256 + threadIdx.x;
    __shared__ float se[512];
    for (int i = threadIdx.x; i < 512; i += 256) {
        float e = emb[b * 512 + i];
        se[i] = e / (1.0f + expf(-e));
    }
    __syncthreads();
    float acc = bias[o];
    #pragma unroll 8
    for (int k = 0; k < 512; ++k)
        acc += se[k] * w[(size_t)k * 3072 + o];
    mod[b * 3072 + o] = acc;
}

// ---------------------------------------------------------------------------
// 2) weight transpose + bf16 cast: Wt[n][k] = bf16(W[k][n])
// ---------------------------------------------------------------------------
__global__ __launch_bounds__(1024)
void transpose_kernel(const float* __restrict__ W, u16* __restrict__ Wt, int K, int N)
{
    __shared__ float tile[32][33];
    int k0 = blockIdx.x * 32, n0 = blockIdx.y * 32;
    tile[threadIdx.y][threadIdx.x] = W[(size_t)(k0 + threadIdx.y) * N + (n0 + threadIdx.x)];
    __syncthreads();
    Wt[(size_t)(n0 + threadIdx.y) * K + (k0 + threadIdx.x)] = f2bf(tile[threadIdx.x][threadIdx.y]);
}

// ---------------------------------------------------------------------------
// 3) LN + adaLN modulate; wave-per-row (4 rows/block), no LDS / syncthreads.
//    fp32 in, bf16 out. Lane owns 8 channels (f32x4 x2 load, 16B bf16 store).
// ---------------------------------------------------------------------------
template<int WINDOWED>
__global__ __launch_bounds__(256)
void ln_kernel(const float* __restrict__ xin, const float* __restrict__ mod,
               u16* __restrict__ out, int shOff, int scOff, int rowBase)
{
    int wv   = threadIdx.x >> 6;
    int lane = threadIdx.x & 63;
    int rbl = blockIdx.x * 4 + wv;        // chunk-local row
    int rb  = rbl + rowBase;              // global sequence row
    int b = rb / L_TOK, l = rb - b * L_TOK;
    const float* xr = xin + (size_t)rb * C_DIM;
    int c0 = lane * 8;
    f32x4 u0 = *(const f32x4*)(xr + c0);
    f32x4 u1 = *(const f32x4*)(xr + c0 + 4);
    float s = u0.x + u0.y + u0.z + u0.w + u1.x + u1.y + u1.z + u1.w;
    float q = u0.x*u0.x + u0.y*u0.y + u0.z*u0.z + u0.w*u0.w
            + u1.x*u1.x + u1.y*u1.y + u1.z*u1.z + u1.w*u1.w;
    #pragma unroll
    for (int off = 32; off > 0; off >>= 1) {
        s += __shfl_xor(s, off);
        q += __shfl_xor(q, off);
    }
    float mu = s * (1.0f / 512.0f);
    float var = q * (1.0f / 512.0f) - mu * mu;
    float rstd = rsqrtf(var + 1e-6f);
    const float* mb = mod + b * 3072;
    f32x4 sc0 = *(const f32x4*)(mb + scOff + c0);
    f32x4 sc1 = *(const f32x4*)(mb + scOff + c0 + 4);
    f32x4 sh0 = *(const f32x4*)(mb + shOff + c0);
    f32x4 sh1 = *(const f32x4*)(mb + shOff + c0 + 4);
    float y[8];
    y[0] = (u0.x - mu) * rstd * (1.0f + sc0.x) + sh0.x;
    y[1] = (u0.y - mu) * rstd * (1.0f + sc0.y) + sh0.y;
    y[2] = (u0.z - mu) * rstd * (1.0f + sc0.z) + sh0.z;
    y[3] = (u0.w - mu) * rstd * (1.0f + sc0.w) + sh0.w;
    y[4] = (u1.x - mu) * rstd * (1.0f + sc1.x) + sh1.x;
    y[5] = (u1.y - mu) * rstd * (1.0f + sc1.y) + sh1.y;
    y[6] = (u1.z - mu) * rstd * (1.0f + sc1.z) + sh1.z;
    y[7] = (u1.w - mu) * rstd * (1.0f + sc1.w) + sh1.w;
    size_t drow;
    if (WINDOWED) {
        int hh = l / HW, ww = l - hh * HW;
        int hs = hh - 3; if (hs < 0) hs += HW;
        int ws2 = ww - 3; if (ws2 < 0) ws2 += HW;
        int wi = (hs / WS7) * 8 + (ws2 / WS7);
        int n  = (hs % WS7) * WS7 + (ws2 % WS7);
        int b_local = rbl / L_TOK;
        drow = (size_t)((b_local * 64 + wi) * NWIN + n);
    } else {
        drow = (size_t)rbl;
    }
    u16x8 o;
    #pragma unroll
    for (int i = 0; i < 8; ++i) o[i] = f2bf(y[i]);
    *(u16x8*)(out + drow * C_DIM + c0) = o;
}

// ---------------------------------------------------------------------------
// 4) GEMM: C[M,N] = A[M,K] @ Bt[N,K]^T + bias
//    128x128 tile, BK=32, 4 waves x (4x4) mfma_f32_16x16x32_bf16.
//    Staging via global_load_lds width=16 (m97 pattern).
// ---------------------------------------------------------------------------
template<int EPI>
__global__ __launch_bounds__(256)
void gemm128(const u16* __restrict__ A, const u16* __restrict__ Bt,
             const float* __restrict__ bias, void* __restrict__ outv,
             const float* __restrict__ resid, const float* __restrict__ mod,
             int N, int K, int rowOffset)
{
    __shared__ u16 sA[128][32];   // unpadded: global_load_lds is lane-contiguous
    __shared__ u16 sB[128][32];
    const int tid  = threadIdx.x;
    const int lane = tid & 63;
    const int wave = tid >> 6;
    const int wr = (wave >> 1) * 64;
    const int wc = (wave & 1) * 64;
    const int quad = lane >> 4;
    const int mrow = lane & 15;
    const int rowBase = blockIdx.x * 128;
    const int colBase = blockIdx.y * 128;

    const int r0   = wave * 32;
    const int lrow = lane >> 2;
    const int lcol = (lane & 3) * 8;          // u16 offset in row
    const u16* gA = A  + (size_t)(rowBase + r0 + lrow) * K + lcol;
    const u16* gB = Bt + (size_t)(colBase + r0 + lrow) * K + lcol;
    u16* lA0 = &sA[r0][0];
    u16* lA1 = &sA[r0 + 16][0];
    u16* lB0 = &sB[r0][0];
    u16* lB1 = &sB[r0 + 16][0];
    const size_t gstep = (size_t)16 * K;

    f32x4 acc[4][4] = {};

    for (int kk = 0; kk < K; kk += 32) {
        __syncthreads();
        gl_lds16(gA + kk,         lA0);
        gl_lds16(gA + kk + gstep, lA1);
        gl_lds16(gB + kk,         lB0);
        gl_lds16(gB + kk + gstep, lB1);
        __syncthreads();
        s16x8 af[4], bg[4];
        #pragma unroll
        for (int tt = 0; tt < 4; ++tt) {
            af[tt] = *(const s16x8*)&sA[wr + tt * 16 + mrow][quad * 8];
            bg[tt] = *(const s16x8*)&sB[wc + tt * 16 + mrow][quad * 8];
        }
        #pragma unroll
        for (int tm = 0; tm < 4; ++tm)
            #pragma unroll
            for (int tn = 0; tn < 4; ++tn)
                acc[tm][tn] = __builtin_amdgcn_mfma_f32_16x16x32_bf16(
                    af[tm], bg[tn], acc[tm][tn], 0, 0, 0);
    }

    #pragma unroll
    for (int tm = 0; tm < 4; ++tm) {
        #pragma unroll
        for (int tn = 0; tn < 4; ++tn) {
            int col = colBase + wc + tn * 16 + mrow;
            float bv = bias[col];
            #pragma unroll
            for (int i = 0; i < 4; ++i) {
                int r = rowBase + wr + tm * 16 + quad * 4 + i;   // chunk-local
                float v = acc[tm][tn][i] + bv;
                if constexpr (EPI == 0) {
                    ((u16*)outv)[(size_t)r * N + col] = f2bf(v);
                } else if constexpr (EPI == 1) {
                    float g = 0.5f * v * (1.0f + erff(v * 0.70710678118654752f));
                    ((u16*)outv)[(size_t)r * N + col] = f2bf(g);
                } else if constexpr (EPI == 2) {
                    int rg = r + rowOffset;        // global window-layout row
                    int b = rg / L_TOK;
                    int rem = rg - b * L_TOK;
                    int wi = rem / NWIN;
                    int n  = rem - wi * NWIN;
                    int hs  = (wi >> 3) * WS7 + n / WS7;
                    int ws2 = (wi & 7) * WS7 + n % WS7;
                    int hh = hs + 3;  if (hh >= HW)  hh -= HW;
                    int ww = ws2 + 3; if (ww >= HW)  ww -= HW;
                    size_t dst = ((size_t)(b * L_TOK + hh * HW + ww)) * C_DIM + col;
                    float g = mod[b * 3072 + 1024 + col];
                    ((float*)outv)[dst] = resid[dst] + g * v;
                } else {  // EPI == 3
                    int rg = r + rowOffset;        // global sequence row
                    int b = rg / L_TOK;
                    size_t dst = (size_t)rg * C_DIM + col;
                    float g = mod[b * 3072 + 2560 + col];
                    ((float*)outv)[dst] = resid[dst] + g * v;
                }
            }
        }
    }
}

// ---------------------------------------------------------------------------
// 5) windowed attention, one block per (chunk-local window, head).
//    K stored TRANSPOSED in LDS (skT[d][m], rows padded to 52): QK^T reads
//    are lane-stride-1. Staging via 16B u16x8 loads (t<196, 1 iter).
//    Softmax: 4-lane groups per row (wave-parallel, __shfl_xor within quad).
// ---------------------------------------------------------------------------
__global__ __launch_bounds__(256)
void attn_kernel(const u16* __restrict__ qkv, const float* __restrict__ bias_table,
                 u16* __restrict__ out)
{
    int w = blockIdx.x;       // chunk-local: b_local*64 + wi
    int h = blockIdx.y;       // 0..15
    int wi = w & 63;
    __shared__ float sq[NWIN][DHEAD];       // broadcast reads
    __shared__ float skT[DHEAD][NWIN + 3];  // 32x52, stride-1 reads
    __shared__ float sv[NWIN][DHEAD];       // stride-1 reads
    __shared__ float sS[NWIN][NWIN + 1];
    int t = threadIdx.x;
    const float scale = 0.17677669529663687f;   // 1/sqrt(32)

    if (t < NWIN * 4) {                      // 196 threads, 1 iteration
        int n = t >> 2, d0 = (t & 3) * 8;
        size_t base = ((size_t)(w * NWIN + n)) * 1536 + h * DHEAD + d0;
        u16x8 qv = *(const u16x8*)(qkv + base);
        u16x8 kv = *(const u16x8*)(qkv + base + 512);
        u16x8 vv = *(const u16x8*)(qkv + base + 1024);
        #pragma unroll
        for (int j = 0; j < 8; ++j) {
            sq[n][d0 + j]  = bf2f(qv[j]) * scale;
            skT[d0 + j][n] = bf2f(kv[j]);
            sv[n][d0 + j]  = bf2f(vv[j]);
        }
    }
    __syncthreads();

    int wh = wi >> 3, ww = wi & 7;
    for (int e = t; e < NWIN * NWIN; e += 256) {
        int n = e / NWIN, m = e - n * NWIN;
        float s = 0.0f;
        #pragma unroll
        for (int d = 0; d < DHEAD; ++d) s += sq[n][d] * skT[d][m];
        int nh_ = n / WS7, nw_ = n % WS7;
        int mh_ = m / WS7, mw_ = m % WS7;
        int idx = (nh_ - mh_ + 6) * 13 + (nw_ - mw_ + 6);
        s += bias_table[idx * NHEAD + h];
        // shift-mask regions on the shifted grid; bands at 49 and 53
        int gnh = wh * WS7 + nh_, gnw = ww * WS7 + nw_;
        int gmh = wh * WS7 + mh_, gmw = ww * WS7 + mw_;
        int rn = (gnh < 49 ? 0 : (gnh < 53 ? 1 : 2)) * 3 + (gnw < 49 ? 0 : (gnw < 53 ? 1 : 2));
        int rm = (gmh < 49 ? 0 : (gmh < 53 ? 1 : 2)) * 3 + (gmw < 49 ? 0 : (gmw < 53 ? 1 : 2));
        if (rn != rm) s -= 100.0f;
        sS[n][m] = s;
    }
    __syncthreads();

    // wave-parallel softmax: 4-lane group per row; shfl masks 1,2 stay in quad
    {
        int gid = t >> 2, li = t & 3;
        if (gid < NWIN) {
            float mx = -1e30f;
            for (int m = li; m < NWIN; m += 4) mx = fmaxf(mx, sS[gid][m]);
            mx = fmaxf(mx, __shfl_xor(mx, 1));
            mx = fmaxf(mx, __shfl_xor(mx, 2));
            float sum = 0.0f;
            for (int m = li; m < NWIN; m += 4) {
                float p = __expf(sS[gid][m] - mx);
                sS[gid][m] = p;
                sum += p;
            }
            sum += __shfl_xor(sum, 1);
            sum += __shfl_xor(sum, 2);
            float inv = 1.0f / sum;
            for (int m = li; m < NWIN; m += 4) sS[gid][m] *= inv;
        }
    }
    __syncthreads();

    for (int e = t; e < NWIN * DHEAD; e += 256) {
        int n = e >> 5, d = e & 31;
        float o = 0.0f;
        #pragma unroll 7
        for (int m = 0; m < NWIN; ++m) o += sS[n][m] * sv[m][d];
        out[((size_t)(w * NWIN + n)) * C_DIM + h * DHEAD + d] = f2bf(o);
    }
}

// ---------------------------------------------------------------------------
// fp32 I/O, bf16 compute core. x2 lives in d_out.
// Workspace: two aliased slots (lifetimes disjoint):
//   slotS = winC -> aoC -> h2C   (CB * 3136 * 512  * 2B per batch)
//   slotL = qkvC -> ffiC         (CB * 3136 * 2048 * 2B per batch)
// CB=4 totals exactly 70,713,344 B == the previously-proven footprint.
// CB=8 (134,938,624 B) selected when ws_size allows: halves launch count,
// doubles every grid (proj/ff2: 392->784 blocks).
// ---------------------------------------------------------------------------
extern "C" void kernel_launch(void* const* d_in, const int* in_sizes, int n_in,
                              void* d_out, int out_size, void* d_ws, size_t ws_size,
                              hipStream_t stream)
{
    const float* x       = (const float*)d_in[0];
    const float* emb     = (const float*)d_in[1];
    const float* adaLN_w = (const float*)d_in[2];
    const float* adaLN_b = (const float*)d_in[3];
    const float* qkv_w   = (const float*)d_in[4];
    const float* qkv_b   = (const float*)d_in[5];
    const float* proj_w  = (const float*)d_in[6];
    const float* proj_b  = (const float*)d_in[7];
    const float* relb    = (const float*)d_in[8];
    const float* ff_w1   = (const float*)d_in[9];
    const float* ff_b1   = (const float*)d_in[10];
    const float* ff_w2   = (const float*)d_in[11];
    const float* ff_b2   = (const float*)d_in[12];
    float* outp = (float*)d_out;

    char* ws = (char*)d_ws;
    float* mod   = (float*)(ws + 0);                  //    196,608 B
    u16* wT_qkv  = (u16*)(ws + 196608);               //  1,572,864 B
    u16* wT_proj = (u16*)(ws + 1769472);              //    524,288 B
    u16* wT_ff1  = (u16*)(ws + 2293760);              //  2,097,152 B
    u16* wT_ff2  = (u16*)(ws + 4390912);              //  2,097,152 B
    char* slots  = ws + 6488064;

    const size_t perB_S = (size_t)L_TOK * C_DIM * sizeof(u16);   //  3,211,264
    const size_t perB_L = (size_t)L_TOK * MLP_DIM * sizeof(u16); // 12,845,056

    int CB = 4;   // 6,488,064 + 4*(perB_S+perB_L) == 70,713,344 (proven fit)
    if (ws_size >= 6488064 + 8 * (perB_S + perB_L)) CB = 8;

    const int nChunks   = B_SZ / CB;
    const int chunkRows = CB * L_TOK;
    u16* slotS = (u16*)slots;                         // winC / aoC / h2C
    u16* slotL = (u16*)(slots + (size_t)CB * perB_S); // qkvC / ffiC

    // prolog (once)
    mod_kernel<<<dim3(12, 16), dim3(256), 0, stream>>>(emb, adaLN_w, adaLN_b, mod);
    transpose_kernel<<<dim3(16, 48), dim3(32, 32), 0, stream>>>(qkv_w,  wT_qkv, 512, 1536);
    transpose_kernel<<<dim3(16, 16), dim3(32, 32), 0, stream>>>(proj_w, wT_proj, 512, 512);
    transpose_kernel<<<dim3(16, 64), dim3(32, 32), 0, stream>>>(ff_w1,  wT_ff1, 512, 2048);
    transpose_kernel<<<dim3(64, 16), dim3(32, 32), 0, stream>>>(ff_w2,  wT_ff2, 2048, 512);

    for (int c = 0; c < nChunks; ++c) {
        int row0 = c * chunkRows;
        // LN1 + modulate + shift + window partition: x[row0..] -> slotS (winC)
        ln_kernel<1><<<dim3(chunkRows / 4), dim3(256), 0, stream>>>(
            x, mod, slotS, 0, 512, row0);
        // qkv GEMM: winC @ wT_qkv -> slotL (qkvC)
        gemm128<0><<<dim3(chunkRows / 128, 12), dim3(256), 0, stream>>>(
            slotS, wT_qkv, qkv_b, slotL, nullptr, mod, 1536, 512, 0);
        // attention: qkvC -> slotS (aoC; winC is dead)
        attn_kernel<<<dim3(CB * 64, 16), dim3(256), 0, stream>>>(slotL, relb, slotS);
        // proj + window reverse + unshift + residual(x) -> d_out (x2, fp32)
        gemm128<2><<<dim3(chunkRows / 128, 4), dim3(256), 0, stream>>>(
            slotS, wT_proj, proj_b, outp, x, mod, 512, 512, row0);
        // LN2 + modulate: d_out[row0..] -> slotS (h2C; aoC is dead)
        ln_kernel<0><<<dim3(chunkRows / 4), dim3(256), 0, stream>>>(
            outp, mod, slotS, 1536, 2048, row0);
        // FF1 + GELU: h2C -> slotL (ffiC; qkvC is dead)
        gemm128<1><<<dim3(chunkRows / 128, 16), dim3(256), 0, stream>>>(
            slotS, wT_ff1, ff_b1, slotL, nullptr, mod, 2048, 512, 0);
        // FF2 + residual(x2) -> d_out
        gemm128<3><<<dim3(chunkRows / 128, 4), dim3(256), 0, stream>>>(
            slotL, wT_ff2, ff_b2, outp, outp, mod, 512, 2048, row0);
    }
}

// Round 2
// 1090.833 us; speedup vs baseline: 1.5502x; 1.1482x over previous
//
#include <hip/hip_runtime.h>
#include <cmath>

typedef unsigned short u16;
typedef unsigned short u16x2 __attribute__((ext_vector_type(2)));
typedef unsigned short u16x4 __attribute__((ext_vector_type(4)));
typedef unsigned short u16x8 __attribute__((ext_vector_type(8)));
typedef short s16x8 __attribute__((ext_vector_type(8)));
typedef float f32x4 __attribute__((ext_vector_type(4)));
typedef float f32x2 __attribute__((ext_vector_type(2)));

#define B_SZ 16
#define HW 56
#define L_TOK 3136      // 56*56
#define C_DIM 512
#define NHEAD 16
#define DHEAD 32
#define WS7 7
#define NWIN 49
#define ROWS_TOTAL 50176   // 16*3136
#define MLP_DIM 2048

__device__ __forceinline__ float bf2f(u16 u) {
    union { unsigned int i; float f; } z;
    z.i = ((unsigned int)u) << 16;
    return z.f;
}
__device__ __forceinline__ u16 f2bf(float f) {
    union { float f; unsigned int i; } z;
    z.f = f;
    unsigned int r = z.i + 0x7fffu + ((z.i >> 16) & 1u);
    return (u16)(r >> 16);
}

// async global->LDS, 16B per lane; LDS dest = wave-uniform base + lane*16
__device__ __forceinline__ void gl_lds16(const u16* g, u16* l) {
    __builtin_amdgcn_global_load_lds(
        (const __attribute__((address_space(1))) unsigned int*)g,
        (__attribute__((address_space(3))) unsigned int*)l,
        16, 0, 0);
}

// ---------------------------------------------------------------------------
// 1) mod = silu(emb) @ adaLN_w + adaLN_b -> fp32 [16,3072]
// ---------------------------------------------------------------------------
__global__ __launch_bounds__(256)
void mod_kernel(const float* __restrict__ emb, const float* __restrict__ w,
                const float* __restrict__ bias, float* __restrict__ mod)
{
    int b = blockIdx.y;
    int o = blockIdx.x * 256 + threadIdx.x;
    __shared__ float se[512];
    for (int i = threadIdx.x; i < 512; i += 256) {
        float e = emb[b * 512 + i];
        se[i] = e / (1.0f + expf(-e));
    }
    __syncthreads();
    float acc = bias[o];
    #pragma unroll 8
    for (int k = 0; k < 512; ++k)
        acc += se[k] * w[(size_t)k * 3072 + o];
    mod[b * 3072 + o] = acc;
}

// ---------------------------------------------------------------------------
// 2) weight transpose + bf16 cast: Wt[n][k] = bf16(W[k][n])
// ---------------------------------------------------------------------------
__global__ __launch_bounds__(1024)
void transpose_kernel(const float* __restrict__ W, u16* __restrict__ Wt, int K, int N)
{
    __shared__ float tile[32][33];
    int k0 = blockIdx.x * 32, n0 = blockIdx.y * 32;
    tile[threadIdx.y][threadIdx.x] = W[(size_t)(k0 + threadIdx.y) * N + (n0 + threadIdx.x)];
    __syncthreads();
    Wt[(size_t)(n0 + threadIdx.y) * K + (k0 + threadIdx.x)] = f2bf(tile[threadIdx.x][threadIdx.y]);
}

// ---------------------------------------------------------------------------
// 3) LN + adaLN modulate; wave-per-row (4 rows/block), no LDS / syncthreads.
// ---------------------------------------------------------------------------
template<int WINDOWED>
__global__ __launch_bounds__(256)
void ln_kernel(const float* __restrict__ xin, const float* __restrict__ mod,
               u16* __restrict__ out, int shOff, int scOff, int rowBase)
{
    int wv   = threadIdx.x >> 6;
    int lane = threadIdx.x & 63;
    int rbl = blockIdx.x * 4 + wv;        // chunk-local row
    int rb  = rbl + rowBase;              // global sequence row
    int b = rb / L_TOK, l = rb - b * L_TOK;
    const float* xr = xin + (size_t)rb * C_DIM;
    int c0 = lane * 8;
    f32x4 u0 = *(const f32x4*)(xr + c0);
    f32x4 u1 = *(const f32x4*)(xr + c0 + 4);
    float s = u0.x + u0.y + u0.z + u0.w + u1.x + u1.y + u1.z + u1.w;
    float q = u0.x*u0.x + u0.y*u0.y + u0.z*u0.z + u0.w*u0.w
            + u1.x*u1.x + u1.y*u1.y + u1.z*u1.z + u1.w*u1.w;
    #pragma unroll
    for (int off = 32; off > 0; off >>= 1) {
        s += __shfl_xor(s, off);
        q += __shfl_xor(q, off);
    }
    float mu = s * (1.0f / 512.0f);
    float var = q * (1.0f / 512.0f) - mu * mu;
    float rstd = rsqrtf(var + 1e-6f);
    const float* mb = mod + b * 3072;
    f32x4 sc0 = *(const f32x4*)(mb + scOff + c0);
    f32x4 sc1 = *(const f32x4*)(mb + scOff + c0 + 4);
    f32x4 sh0 = *(const f32x4*)(mb + shOff + c0);
    f32x4 sh1 = *(const f32x4*)(mb + shOff + c0 + 4);
    float y[8];
    y[0] = (u0.x - mu) * rstd * (1.0f + sc0.x) + sh0.x;
    y[1] = (u0.y - mu) * rstd * (1.0f + sc0.y) + sh0.y;
    y[2] = (u0.z - mu) * rstd * (1.0f + sc0.z) + sh0.z;
    y[3] = (u0.w - mu) * rstd * (1.0f + sc0.w) + sh0.w;
    y[4] = (u1.x - mu) * rstd * (1.0f + sc1.x) + sh1.x;
    y[5] = (u1.y - mu) * rstd * (1.0f + sc1.y) + sh1.y;
    y[6] = (u1.z - mu) * rstd * (1.0f + sc1.z) + sh1.z;
    y[7] = (u1.w - mu) * rstd * (1.0f + sc1.w) + sh1.w;
    size_t drow;
    if (WINDOWED) {
        int hh = l / HW, ww = l - hh * HW;
        int hs = hh - 3; if (hs < 0) hs += HW;
        int ws2 = ww - 3; if (ws2 < 0) ws2 += HW;
        int wi = (hs / WS7) * 8 + (ws2 / WS7);
        int n  = (hs % WS7) * WS7 + (ws2 % WS7);
        int b_local = rbl / L_TOK;
        drow = (size_t)((b_local * 64 + wi) * NWIN + n);
    } else {
        drow = (size_t)rbl;
    }
    u16x8 o;
    #pragma unroll
    for (int i = 0; i < 8; ++i) o[i] = f2bf(y[i]);
    *(u16x8*)(out + drow * C_DIM + c0) = o;
}

// ---------------------------------------------------------------------------
// 4) GEMM: C[M,N] = A[M,K] @ Bt[N,K]^T + bias
//    128x128 tile, BK=32, 4 waves x (4x4) mfma_f32_16x16x32_bf16.
// ---------------------------------------------------------------------------
template<int EPI>
__global__ __launch_bounds__(256)
void gemm128(const u16* __restrict__ A, const u16* __restrict__ Bt,
             const float* __restrict__ bias, void* __restrict__ outv,
             const float* __restrict__ resid, const float* __restrict__ mod,
             int N, int K, int rowOffset)
{
    __shared__ u16 sA[128][32];   // unpadded: global_load_lds is lane-contiguous
    __shared__ u16 sB[128][32];
    const int tid  = threadIdx.x;
    const int lane = tid & 63;
    const int wave = tid >> 6;
    const int wr = (wave >> 1) * 64;
    const int wc = (wave & 1) * 64;
    const int quad = lane >> 4;
    const int mrow = lane & 15;
    const int rowBase = blockIdx.x * 128;
    const int colBase = blockIdx.y * 128;

    const int r0   = wave * 32;
    const int lrow = lane >> 2;
    const int lcol = (lane & 3) * 8;          // u16 offset in row
    const u16* gA = A  + (size_t)(rowBase + r0 + lrow) * K + lcol;
    const u16* gB = Bt + (size_t)(colBase + r0 + lrow) * K + lcol;
    u16* lA0 = &sA[r0][0];
    u16* lA1 = &sA[r0 + 16][0];
    u16* lB0 = &sB[r0][0];
    u16* lB1 = &sB[r0 + 16][0];
    const size_t gstep = (size_t)16 * K;

    f32x4 acc[4][4] = {};

    for (int kk = 0; kk < K; kk += 32) {
        __syncthreads();
        gl_lds16(gA + kk,         lA0);
        gl_lds16(gA + kk + gstep, lA1);
        gl_lds16(gB + kk,         lB0);
        gl_lds16(gB + kk + gstep, lB1);
        __syncthreads();
        s16x8 af[4], bg[4];
        #pragma unroll
        for (int tt = 0; tt < 4; ++tt) {
            af[tt] = *(const s16x8*)&sA[wr + tt * 16 + mrow][quad * 8];
            bg[tt] = *(const s16x8*)&sB[wc + tt * 16 + mrow][quad * 8];
        }
        #pragma unroll
        for (int tm = 0; tm < 4; ++tm)
            #pragma unroll
            for (int tn = 0; tn < 4; ++tn)
                acc[tm][tn] = __builtin_amdgcn_mfma_f32_16x16x32_bf16(
                    af[tm], bg[tn], acc[tm][tn], 0, 0, 0);
    }

    #pragma unroll
    for (int tm = 0; tm < 4; ++tm) {
        #pragma unroll
        for (int tn = 0; tn < 4; ++tn) {
            int col = colBase + wc + tn * 16 + mrow;
            float bv = bias[col];
            #pragma unroll
            for (int i = 0; i < 4; ++i) {
                int r = rowBase + wr + tm * 16 + quad * 4 + i;   // chunk-local
                float v = acc[tm][tn][i] + bv;
                if constexpr (EPI == 0) {
                    ((u16*)outv)[(size_t)r * N + col] = f2bf(v);
                } else if constexpr (EPI == 1) {
                    float g = 0.5f * v * (1.0f + erff(v * 0.70710678118654752f));
                    ((u16*)outv)[(size_t)r * N + col] = f2bf(g);
                } else if constexpr (EPI == 2) {
                    int rg = r + rowOffset;        // global window-layout row
                    int b = rg / L_TOK;
                    int rem = rg - b * L_TOK;
                    int wi = rem / NWIN;
                    int n  = rem - wi * NWIN;
                    int hs  = (wi >> 3) * WS7 + n / WS7;
                    int ws2 = (wi & 7) * WS7 + n % WS7;
                    int hh = hs + 3;  if (hh >= HW)  hh -= HW;
                    int ww = ws2 + 3; if (ww >= HW)  ww -= HW;
                    size_t dst = ((size_t)(b * L_TOK + hh * HW + ww)) * C_DIM + col;
                    float g = mod[b * 3072 + 1024 + col];
                    ((float*)outv)[dst] = resid[dst] + g * v;
                } else {  // EPI == 3
                    int rg = r + rowOffset;        // global sequence row
                    int b = rg / L_TOK;
                    size_t dst = (size_t)rg * C_DIM + col;
                    float g = mod[b * 3072 + 2560 + col];
                    ((float*)outv)[dst] = resid[dst] + g * v;
                }
            }
        }
    }
}

// ---------------------------------------------------------------------------
// 5) MFMA windowed attention. Block = 4 waves = 4 heads of one window.
//    grid (CB*64 windows, 4 head-groups); wave handles head hg*4+wave.
//    QK^T: 16x mfma_16x16x32 (K=32, 49 rows padded to 64, pad rows clamped).
//    Softmax: shfl_xor over the 16-lane fragment groups (row spread =
//    16 lanes x 4 regs). P normalized, bf16-packed pairwise (shfl_xor 1),
//    written conflict-free into per-wave sP[64][72].
//    PV: O^T = mfma(V^T-frag from sVt, P-frag from sP), 16 mfma.
//    No cross-wave LDS sharing -> 2 barriers total.
// ---------------------------------------------------------------------------
__global__ __launch_bounds__(256)
void attn_mfma(const u16* __restrict__ qkv, const float* __restrict__ bias_table,
               u16* __restrict__ out)
{
    const int w    = blockIdx.x;          // chunk-local: b_local*64 + wi
    const int hg   = blockIdx.y;          // 0..3
    const int wave = threadIdx.x >> 6;
    const int lane = threadIdx.x & 63;
    const int h    = hg * 4 + wave;
    const int wi   = w & 63;
    const int quad = lane >> 4;
    const int mrow = lane & 15;

    __shared__ u16 sP[4][64][72];      // per-wave P (bf16), pitch 72 (144B rows)
    __shared__ u16 sVt[4][32][72];     // per-wave V^T (bf16)
    __shared__ float sBias[4][169];    // per-wave head bias slice

    const u16* qb = qkv + (size_t)w * NWIN * 1536 + h * DHEAD;

    // stage per-head bias slice (strided global, L2-resident table)
    for (int e = lane; e < 169; e += 64)
        sBias[wave][e] = bias_table[e * NHEAD + h];

    // stage V transposed: rows 0..48 real, 49..63 zeroed (pad cols of P are 0
    // anyway, but keep LDS finite so 0*x can't be NaN)
    #pragma unroll
    for (int rr = 0; rr < 4; ++rr) {
        int e = rr * 64 + lane;
        int r = e >> 2, d0 = (e & 3) * 8;
        u16x8 vv = {};
        if (e < 196)
            vv = *(const u16x8*)(qb + (size_t)r * 1536 + 1024 + d0);
        #pragma unroll
        for (int j = 0; j < 8; ++j)
            sVt[wave][d0 + j][r] = vv[j];
    }

    // Q/K fragments direct from global; pad rows (49..63) clamped to 48
    s16x8 qf[4], kf[4];
    #pragma unroll
    for (int t = 0; t < 4; ++t) {
        int r = t * 16 + mrow; if (r > 48) r = 48;
        qf[t] = *(const s16x8*)(qb + (size_t)r * 1536 + quad * 8);
        kf[t] = *(const s16x8*)(qb + (size_t)r * 1536 + 512 + quad * 8);
    }
    __syncthreads();   // sVt / sBias visible (also wave-local write->read fence)

    // S = Q K^T : S[m][n], m = tm*16+quad*4+i, n = tn*16+mrow
    f32x4 sacc[4][4] = {};
    #pragma unroll
    for (int tm = 0; tm < 4; ++tm)
        #pragma unroll
        for (int tn = 0; tn < 4; ++tn)
            sacc[tm][tn] = __builtin_amdgcn_mfma_f32_16x16x32_bf16(
                qf[tm], kf[tn], sacc[tm][tn], 0, 0, 0);

    const float scale = 0.17677669529663687f;   // 1/sqrt(32)
    const int wh = wi >> 3, ww = wi & 7;

    // per-lane key-side terms (constant across tm,i)
    int khA[4], kwA[4], rkA[4], nOK[4];
    #pragma unroll
    for (int tn = 0; tn < 4; ++tn) {
        int n = tn * 16 + mrow;
        nOK[tn] = (n < NWIN);
        int nc = n > 48 ? 48 : n;
        khA[tn] = nc / 7; kwA[tn] = nc - khA[tn] * 7;
        int gkh = wh * 7 + khA[tn], gkw = ww * 7 + kwA[tn];
        rkA[tn] = (gkh < 49 ? 0 : (gkh < 53 ? 1 : 2)) * 3
                + (gkw < 49 ? 0 : (gkw < 53 ? 1 : 2));
    }

    #pragma unroll
    for (int tm = 0; tm < 4; ++tm) {
        #pragma unroll
        for (int i = 0; i < 4; ++i) {
            int m = tm * 16 + quad * 4 + i;
            int mc = m > 48 ? 48 : m;            // garbage rows: keep idx bounded
            int qh = mc / 7, qw = mc - qh * 7;
            int gqh = wh * 7 + qh, gqw = ww * 7 + qw;
            int rq = (gqh < 49 ? 0 : (gqh < 53 ? 1 : 2)) * 3
                   + (gqw < 49 ? 0 : (gqw < 53 ? 1 : 2));
            float v[4];
            #pragma unroll
            for (int tn = 0; tn < 4; ++tn) {
                float s = sacc[tm][tn][i] * scale;
                s += sBias[wave][(qh - khA[tn] + 6) * 13 + (qw - kwA[tn] + 6)];
                if (rq != rkA[tn]) s -= 100.0f;
                v[tn] = nOK[tn] ? s : -1e30f;
            }
            float mx = fmaxf(fmaxf(v[0], v[1]), fmaxf(v[2], v[3]));
            mx = fmaxf(mx, __shfl_xor(mx, 1));
            mx = fmaxf(mx, __shfl_xor(mx, 2));
            mx = fmaxf(mx, __shfl_xor(mx, 4));
            mx = fmaxf(mx, __shfl_xor(mx, 8));
            float p0 = __expf(v[0] - mx), p1 = __expf(v[1] - mx);
            float p2 = __expf(v[2] - mx), p3 = __expf(v[3] - mx);
            float sum = p0 + p1 + p2 + p3;
            sum += __shfl_xor(sum, 1);
            sum += __shfl_xor(sum, 2);
            sum += __shfl_xor(sum, 4);
            sum += __shfl_xor(sum, 8);
            float inv = 1.0f / sum;
            float pp[4] = { p0 * inv, p1 * inv, p2 * inv, p3 * inv };
            // pack (n, n+1) bf16 pairs via neighbor shfl; even-mrow lanes write
            #pragma unroll
            for (int tn = 0; tn < 4; ++tn) {
                float po = __shfl_xor(pp[tn], 1);
                if (!(mrow & 1)) {
                    unsigned int pk = (unsigned int)f2bf(pp[tn])
                                    | ((unsigned int)f2bf(po) << 16);
                    *(unsigned int*)&sP[wave][m][tn * 16 + mrow] = pk;
                }
            }
        }
    }
    __syncthreads();   // sP ready

    // O^T[d][m] = sum_n V[n][d] * P[m][n] ; A = V^T frags, B = P frags
    f32x4 oacc[2][4] = {};
    #pragma unroll
    for (int ks = 0; ks < 2; ++ks) {
        s16x8 vf[2], pf[4];
        #pragma unroll
        for (int td = 0; td < 2; ++td)
            vf[td] = *(const s16x8*)&sVt[wave][td * 16 + mrow][ks * 32 + quad * 8];
        #pragma unroll
        for (int tm = 0; tm < 4; ++tm)
            pf[tm] = *(const s16x8*)&sP[wave][tm * 16 + mrow][ks * 32 + quad * 8];
        #pragma unroll
        for (int td = 0; td < 2; ++td)
            #pragma unroll
            for (int tm = 0; tm < 4; ++tm)
                oacc[td][tm] = __builtin_amdgcn_mfma_f32_16x16x32_bf16(
                    vf[td], pf[tm], oacc[td][tm], 0, 0, 0);
    }

    // store: lane holds O^T[d = td*16+quad*4+i][m = tm*16+mrow]
    #pragma unroll
    for (int tm = 0; tm < 4; ++tm) {
        int m = tm * 16 + mrow;
        if (m < NWIN) {
            u16* orow = out + ((size_t)(w * NWIN + m)) * C_DIM + h * DHEAD;
            #pragma unroll
            for (int td = 0; td < 2; ++td) {
                u16x4 ov;
                #pragma unroll
                for (int i = 0; i < 4; ++i) ov[i] = f2bf(oacc[td][tm][i]);
                *(u16x4*)(orow + td * 16 + quad * 4) = ov;
            }
        }
    }
}

// ---------------------------------------------------------------------------
// fp32 I/O, bf16 compute core. x2 lives in d_out.
// Workspace: two aliased slots (lifetimes disjoint):
//   slotS = winC -> aoC -> h2C   (CB * 3136 * 512  * 2B per batch)
//   slotL = qkvC -> ffiC         (CB * 3136 * 2048 * 2B per batch)
// CB=4 totals exactly 70,713,344 B == the previously-proven footprint.
// ---------------------------------------------------------------------------
extern "C" void kernel_launch(void* const* d_in, const int* in_sizes, int n_in,
                              void* d_out, int out_size, void* d_ws, size_t ws_size,
                              hipStream_t stream)
{
    const float* x       = (const float*)d_in[0];
    const float* emb     = (const float*)d_in[1];
    const float* adaLN_w = (const float*)d_in[2];
    const float* adaLN_b = (const float*)d_in[3];
    const float* qkv_w   = (const float*)d_in[4];
    const float* qkv_b   = (const float*)d_in[5];
    const float* proj_w  = (const float*)d_in[6];
    const float* proj_b  = (const float*)d_in[7];
    const float* relb    = (const float*)d_in[8];
    const float* ff_w1   = (const float*)d_in[9];
    const float* ff_b1   = (const float*)d_in[10];
    const float* ff_w2   = (const float*)d_in[11];
    const float* ff_b2   = (const float*)d_in[12];
    float* outp = (float*)d_out;

    char* ws = (char*)d_ws;
    float* mod   = (float*)(ws + 0);                  //    196,608 B
    u16* wT_qkv  = (u16*)(ws + 196608);               //  1,572,864 B
    u16* wT_proj = (u16*)(ws + 1769472);              //    524,288 B
    u16* wT_ff1  = (u16*)(ws + 2293760);              //  2,097,152 B
    u16* wT_ff2  = (u16*)(ws + 4390912);              //  2,097,152 B
    char* slots  = ws + 6488064;

    const size_t perB_S = (size_t)L_TOK * C_DIM * sizeof(u16);   //  3,211,264
    const size_t perB_L = (size_t)L_TOK * MLP_DIM * sizeof(u16); // 12,845,056

    int CB = 4;   // 6,488,064 + 4*(perB_S+perB_L) == 70,713,344 (proven fit)
    if (ws_size >= 6488064 + 8 * (perB_S + perB_L)) CB = 8;

    const int nChunks   = B_SZ / CB;
    const int chunkRows = CB * L_TOK;
    u16* slotS = (u16*)slots;                         // winC / aoC / h2C
    u16* slotL = (u16*)(slots + (size_t)CB * perB_S); // qkvC / ffiC

    // prolog (once)
    mod_kernel<<<dim3(12, 16), dim3(256), 0, stream>>>(emb, adaLN_w, adaLN_b, mod);
    transpose_kernel<<<dim3(16, 48), dim3(32, 32), 0, stream>>>(qkv_w,  wT_qkv, 512, 1536);
    transpose_kernel<<<dim3(16, 16), dim3(32, 32), 0, stream>>>(proj_w, wT_proj, 512, 512);
    transpose_kernel<<<dim3(16, 64), dim3(32, 32), 0, stream>>>(ff_w1,  wT_ff1, 512, 2048);
    transpose_kernel<<<dim3(64, 16), dim3(32, 32), 0, stream>>>(ff_w2,  wT_ff2, 2048, 512);

    for (int c = 0; c < nChunks; ++c) {
        int row0 = c * chunkRows;
        // LN1 + modulate + shift + window partition: x[row0..] -> slotS (winC)
        ln_kernel<1><<<dim3(chunkRows / 4), dim3(256), 0, stream>>>(
            x, mod, slotS, 0, 512, row0);
        // qkv GEMM: winC @ wT_qkv -> slotL (qkvC)
        gemm128<0><<<dim3(chunkRows / 128, 12), dim3(256), 0, stream>>>(
            slotS, wT_qkv, qkv_b, slotL, nullptr, mod, 1536, 512, 0);
        // attention (MFMA): qkvC -> slotS (aoC; winC is dead)
        attn_mfma<<<dim3(CB * 64, 4), dim3(256), 0, stream>>>(slotL, relb, slotS);
        // proj + window reverse + unshift + residual(x) -> d_out (x2, fp32)
        gemm128<2><<<dim3(chunkRows / 128, 4), dim3(256), 0, stream>>>(
            slotS, wT_proj, proj_b, outp, x, mod, 512, 512, row0);
        // LN2 + modulate: d_out[row0..] -> slotS (h2C; aoC is dead)
        ln_kernel<0><<<dim3(chunkRows / 4), dim3(256), 0, stream>>>(
            outp, mod, slotS, 1536, 2048, row0);
        // FF1 + GELU: h2C -> slotL (ffiC; qkvC is dead)
        gemm128<1><<<dim3(chunkRows / 128, 16), dim3(256), 0, stream>>>(
            slotS, wT_ff1, ff_b1, slotL, nullptr, mod, 2048, 512, 0);
        // FF2 + residual(x2) -> d_out
        gemm128<3><<<dim3(chunkRows / 128, 4), dim3(256), 0, stream>>>(
            slotL, wT_ff2, ff_b2, outp, outp, mod, 512, 2048, row0);
    }
}